// Round 4
// baseline (207.737 us; speedup 1.0000x reference)
//
#include <hip/hip_runtime.h>
#include <math.h>

#define Bb   4
#define Nn   2048
#define Dd   256
#define Hh   4
#define HDd  64

typedef float v4f __attribute__((ext_vector_type(4)));
typedef short v8s __attribute__((ext_vector_type(8)));

__device__ __forceinline__ unsigned rne_bf16(float f) {
    unsigned u = __float_as_uint(f);
    u += 0x7fffu + ((u >> 16) & 1u);
    return u >> 16;
}

// ---------------------------------------------------------------------------
// Kernel 1: h = x @ W.T  (M=8192, N=256, K=256), 64x64 tile, 4x4/thread.
// Prologue: zero-fill d_out + zbuf (replaces 2 memset dispatches).
// Epilogue: s_src/s_dst via shfl reduce; h -> bf16 (hi only), TRANSPOSED-TILED
//           [b][jb(64)][h][d(64)][j(32)].
// ---------------------------------------------------------------------------
__global__ __launch_bounds__(256) void k_gemm(const float* __restrict__ x,
                                              const float* __restrict__ W,
                                              const float* __restrict__ a_src,
                                              const float* __restrict__ a_dst,
                                              unsigned short* __restrict__ hbf,
                                              float* __restrict__ ssrc,
                                              float* __restrict__ sdst,
                                              float4* __restrict__ zbuf4,
                                              float4* __restrict__ out4) {
    __shared__ __align__(16) float smem[4352];   // xs [0,2176) ws [2176,4352); reused 64x65
    const int tid = threadIdx.x;
    // ---- zero-fill prologue: out (524288 f4 / 512 blocks), zbuf (8192 f4) ----
    {
        float4 z4 = make_float4(0.f, 0.f, 0.f, 0.f);
#pragma unroll
        for (int s = 0; s < 4; ++s)
            out4[(size_t)blockIdx.x * 1024 + s * 256 + tid] = z4;
        if (tid < 16) zbuf4[(size_t)blockIdx.x * 16 + tid] = z4;
    }
    const int m0 = (int)(blockIdx.x >> 2) * 64;
    const int n0 = (int)(blockIdx.x & 3) * 64;
    const int tx = tid & 15, ty = tid >> 4;
    const int b = m0 >> 11;
    const int head = n0 >> 6;

    float4 acc[4];
#pragma unroll
    for (int r = 0; r < 4; ++r) acc[r] = make_float4(0.f, 0.f, 0.f, 0.f);

    for (int k0 = 0; k0 < Dd; k0 += 32) {
        __syncthreads();
#pragma unroll
        for (int s = 0; s < 2; ++s) {
            int slot = tid + s * 256;
            int row = slot >> 3, kv = slot & 7;
            float4 xv = *(const float4*)(x + (size_t)(m0 + row) * Dd + k0 + kv * 4);
            float4 wv = *(const float4*)(W + (size_t)(n0 + row) * Dd + k0 + kv * 4);
            smem[(kv * 4 + 0) * 68 + row] = xv.x; smem[(kv * 4 + 1) * 68 + row] = xv.y;
            smem[(kv * 4 + 2) * 68 + row] = xv.z; smem[(kv * 4 + 3) * 68 + row] = xv.w;
            smem[2176 + (kv * 4 + 0) * 68 + row] = wv.x; smem[2176 + (kv * 4 + 1) * 68 + row] = wv.y;
            smem[2176 + (kv * 4 + 2) * 68 + row] = wv.z; smem[2176 + (kv * 4 + 3) * 68 + row] = wv.w;
        }
        __syncthreads();
#pragma unroll
        for (int kk = 0; kk < 32; ++kk) {
            float4 a = *(const float4*)(smem + kk * 68 + ty * 4);
            float4 bq = *(const float4*)(smem + 2176 + kk * 68 + tx * 4);
            acc[0].x = fmaf(a.x, bq.x, acc[0].x); acc[0].y = fmaf(a.x, bq.y, acc[0].y);
            acc[0].z = fmaf(a.x, bq.z, acc[0].z); acc[0].w = fmaf(a.x, bq.w, acc[0].w);
            acc[1].x = fmaf(a.y, bq.x, acc[1].x); acc[1].y = fmaf(a.y, bq.y, acc[1].y);
            acc[1].z = fmaf(a.y, bq.z, acc[1].z); acc[1].w = fmaf(a.y, bq.w, acc[1].w);
            acc[2].x = fmaf(a.z, bq.x, acc[2].x); acc[2].y = fmaf(a.z, bq.y, acc[2].y);
            acc[2].z = fmaf(a.z, bq.z, acc[2].z); acc[2].w = fmaf(a.z, bq.w, acc[2].w);
            acc[3].x = fmaf(a.w, bq.x, acc[3].x); acc[3].y = fmaf(a.w, bq.y, acc[3].y);
            acc[3].z = fmaf(a.w, bq.z, acc[3].z); acc[3].w = fmaf(a.w, bq.w, acc[3].w);
        }
    }

    // ---- scores epilogue ----
    {
        float4 as4 = *(const float4*)(a_src + head * HDd + tx * 4);
        float4 ad4 = *(const float4*)(a_dst + head * HDd + tx * 4);
#pragma unroll
        for (int r = 0; r < 4; ++r) {
            float ss = acc[r].x * as4.x + acc[r].y * as4.y + acc[r].z * as4.z + acc[r].w * as4.w;
            float sd = acc[r].x * ad4.x + acc[r].y * ad4.y + acc[r].z * ad4.z + acc[r].w * ad4.w;
#pragma unroll
            for (int off = 1; off < 16; off <<= 1) {
                ss += __shfl_xor(ss, off);
                sd += __shfl_xor(sd, off);
            }
            if (tx == 0) {
                int i = (m0 & 2047) + ty * 4 + r;
                ssrc[((size_t)b * Nn + i) * Hh + head] = ss;
                sdst[((size_t)b * Nn + i) * Hh + head] = sd;
            }
        }
    }

    // ---- transpose + bf16 (hi only) tiled write ----
    __syncthreads();
#pragma unroll
    for (int r = 0; r < 4; ++r) {
        smem[(tx * 4 + 0) * 65 + ty * 4 + r] = acc[r].x;
        smem[(tx * 4 + 1) * 65 + ty * 4 + r] = acc[r].y;
        smem[(tx * 4 + 2) * 65 + ty * 4 + r] = acc[r].z;
        smem[(tx * 4 + 3) * 65 + ty * 4 + r] = acc[r].w;
    }
    __syncthreads();
    if (tid < 128) {
        const int dloc = tid >> 1, jh = tid & 1;
        const float* row = smem + dloc * 65 + jh * 32;
        unsigned pk[16];
#pragma unroll
        for (int jj = 0; jj < 16; ++jj) {
            unsigned u0 = rne_bf16(row[jj * 2]);
            unsigned u1 = rne_bf16(row[jj * 2 + 1]);
            pk[jj] = u0 | (u1 << 16);
        }
        int jbglob = ((m0 & 2047) >> 5) + jh;
        unsigned short* dst = hbf +
            ((size_t)((b * 64 + jbglob) * 256 + head * HDd + dloc)) * 32;
        uint4* d4 = (uint4*)dst;
        d4[0] = make_uint4(pk[0], pk[1], pk[2], pk[3]);
        d4[1] = make_uint4(pk[4], pk[5], pk[6], pk[7]);
        d4[2] = make_uint4(pk[8], pk[9], pk[10], pk[11]);
        d4[3] = make_uint4(pk[12], pk[13], pk[14], pk[15]);
    }
}

// ---------------------------------------------------------------------------
// Kernel 2: MFMA masked-softmax aggregate, hi-only h.
// Block = (b, i-tile 64, j-split of 8) -> grid 1024 (3 blocks/CU by LDS).
// Per 32-j step: reg-prefetch hbf row + adj before barrier; stage Bh; gen w~
// (bf16 RNE, Z from rounded values) into A-layout Aw; 16 MFMAs/wave.
// Partials -> unsafeAtomicAdd into zeroed out/zbuf.
// ---------------------------------------------------------------------------
__global__ __launch_bounds__(256, 3) void k_aggr(const unsigned short* __restrict__ hbf,
                                                 const float* __restrict__ adj,
                                                 const float* __restrict__ ssrc,
                                                 const float* __restrict__ sdst,
                                                 float* __restrict__ out,
                                                 float* __restrict__ zbuf) {
    __shared__ __align__(16) unsigned short Bh[256 * 40];  // [h*64+d] rows, 80 B stride
    __shared__ __align__(16) unsigned short Aw[256 * 40];  // [h*64+i] rows

    const int tid = threadIdx.x;
    const int it = (int)blockIdx.x & 31;
    const int b  = ((int)blockIdx.x >> 5) & 3;
    const int js = (int)blockIdx.x >> 7;      // 0..7
    const int i0 = it * 64;

    const int gi = tid >> 2;       // 0..63
    const int gj8 = tid & 3;       // 8 j's x 4 heads
    const int wv = tid >> 6;       // head
    const int ln = tid & 63, l15 = ln & 15, l4 = ln >> 4;

    const float4 s4 = *(const float4*)(ssrc + ((size_t)b * Nn + i0 + gi) * Hh);
    const float s4h[4] = {s4.x, s4.y, s4.z, s4.w};
    const float* adjr = adj + (size_t)b * Nn * Nn + (size_t)(i0 + gi) * Nn;
    const float* sdr = sdst + (size_t)b * Nn * Hh;

    float zp[4] = {0.f, 0.f, 0.f, 0.f};
    v4f acc[4][4];
#pragma unroll
    for (int g = 0; g < 4; ++g)
#pragma unroll
        for (int t = 0; t < 4; ++t)
            acc[g][t] = (v4f){0.f, 0.f, 0.f, 0.f};

    for (int st = 0; st < 8; ++st) {
        const int j0 = js * 256 + st * 32;
        const int jb = js * 8 + st;
        // ---- register prefetch (global, overlaps previous step's MFMA) ----
        const uint4* src = (const uint4*)(hbf + ((size_t)(b * 64 + jb) * 256 + tid) * 32);
        uint4 p0 = src[0], p1 = src[1], p2 = src[2], p3 = src[3];
        float4 aj0 = *(const float4*)(adjr + j0 + gj8 * 8);
        float4 aj1 = *(const float4*)(adjr + j0 + gj8 * 8 + 4);
        __syncthreads();   // previous step's LDS readers done
        // ---- stage Bh: thread = row (h*64+d), 64 B ----
        {
            uint4* dh = (uint4*)(Bh + tid * 40);
            dh[0] = p0; dh[1] = p1; dh[2] = p2; dh[3] = p3;
        }
        // ---- generate w~ tile into A layout ----
        {
            const float adjv[8] = {aj0.x, aj0.y, aj0.z, aj0.w, aj1.x, aj1.y, aj1.z, aj1.w};
            unsigned wpk[4][4];
#pragma unroll
            for (int jj = 0; jj < 8; ++jj) {
                float4 sdv = *(const float4*)(sdr + (size_t)(j0 + gj8 * 8 + jj) * Hh);
                const float sdh[4] = {sdv.x, sdv.y, sdv.z, sdv.w};
#pragma unroll
                for (int h = 0; h < 4; ++h) {
                    float e = s4h[h] + sdh[h];
                    e = (e > 0.f) ? e : 0.2f * e;
                    float wvv = adjv[jj] * __expf(e);
                    unsigned us = rne_bf16(wvv);
                    zp[h] += __uint_as_float(us << 16);
                    if (jj & 1) wpk[h][jj >> 1] |= (us << 16);
                    else        wpk[h][jj >> 1] = us;
                }
            }
#pragma unroll
            for (int h = 0; h < 4; ++h)
                *(uint4*)(Aw + (h * 64 + gi) * 40 + gj8 * 8) =
                    make_uint4(wpk[h][0], wpk[h][1], wpk[h][2], wpk[h][3]);
        }
        __syncthreads();
        // ---- MFMA phase: wave = head, 16 MFMAs ----
        {
            v8s a[4];
#pragma unroll
            for (int g = 0; g < 4; ++g)
                a[g] = *(const v8s*)(Aw + (wv * 64 + g * 16 + l15) * 40 + l4 * 8);
#pragma unroll
            for (int t = 0; t < 4; ++t) {
                v8s bh = *(const v8s*)(Bh + (wv * 64 + t * 16 + l15) * 40 + l4 * 8);
#pragma unroll
                for (int g = 0; g < 4; ++g)
                    acc[g][t] = __builtin_amdgcn_mfma_f32_16x16x32_bf16(a[g], bh, acc[g][t], 0, 0, 0);
            }
        }
    }

    // ---- epilogue: atomic partial out + Z ----
#pragma unroll
    for (int h = 0; h < 4; ++h) {
        float zz = zp[h];
        zz += __shfl_xor(zz, 1);
        zz += __shfl_xor(zz, 2);
        if (gj8 == 0)
            unsafeAtomicAdd(zbuf + ((size_t)b * Nn + i0 + gi) * Hh + h, zz);
    }
#pragma unroll
    for (int g = 0; g < 4; ++g)
#pragma unroll
        for (int t = 0; t < 4; ++t)
#pragma unroll
            for (int r = 0; r < 4; ++r) {
                int il = g * 16 + l4 * 4 + r;
                int d = wv * HDd + t * 16 + l15;
                unsafeAtomicAdd(out + ((size_t)b * Nn + i0 + il) * Dd + d, acc[g][t][r]);
            }
}

// ---------------------------------------------------------------------------
// Kernel 3: out /= Z   (float4 units; grid 2048)
// ---------------------------------------------------------------------------
__global__ __launch_bounds__(256) void k_fin(float4* __restrict__ out4,
                                             const float* __restrict__ zbuf) {
    size_t q = (size_t)blockIdx.x * 256 + threadIdx.x;
    int bn = (int)(q >> 6), dq = (int)(q & 63);
    float zi = 1.f / zbuf[(size_t)bn * Hh + (dq >> 4)];
    float4 v = out4[q];
    v.x *= zi; v.y *= zi; v.z *= zi; v.w *= zi;
    out4[q] = v;
}

extern "C" void kernel_launch(void* const* d_in, const int* in_sizes, int n_in,
                              void* d_out, int out_size, void* d_ws, size_t ws_size,
                              hipStream_t stream) {
    const float* x     = (const float*)d_in[0];
    const float* adj   = (const float*)d_in[1];
    const float* W     = (const float*)d_in[2];
    const float* a_src = (const float*)d_in[3];
    const float* a_dst = (const float*)d_in[4];
    float* out = (float*)d_out;

    // ws: hbf 4MB | ssrc 128KB | sdst 128KB | zbuf 128KB
    unsigned short* hbf = (unsigned short*)d_ws;
    float* ssrc = (float*)(hbf + (size_t)Bb * Nn * Dd);
    float* sdst = ssrc + (size_t)Bb * Nn * Hh;
    float* zbuf = sdst + (size_t)Bb * Nn * Hh;

    k_gemm<<<dim3(512), dim3(256), 0, stream>>>(x, W, a_src, a_dst, hbf, ssrc, sdst,
                                                (float4*)zbuf, (float4*)out);
    k_aggr<<<dim3(1024), dim3(256), 0, stream>>>(hbf, adj, ssrc, sdst, out, zbuf);
    k_fin <<<dim3(2048), dim3(256), 0, stream>>>((float4*)out, zbuf);
}

// Round 5
// 186.719 us; speedup vs baseline: 1.1126x; 1.1126x over previous
//
#include <hip/hip_runtime.h>
#include <math.h>

#define Bb   4
#define Nn   2048
#define Dd   256
#define Hh   4
#define HDd  64

typedef float v4f __attribute__((ext_vector_type(4)));
typedef short v8s __attribute__((ext_vector_type(8)));

__device__ __forceinline__ unsigned rne_bf16(float f) {
    unsigned u = __float_as_uint(f);
    u += 0x7fffu + ((u >> 16) & 1u);
    return u >> 16;
}

// ---------------------------------------------------------------------------
// Kernel 1: h = x @ W.T  (M=8192, N=256, K=256), 64x64 tile, 4x4/thread.
// Epilogue: s_src/s_dst via shfl reduce; h -> bf16, TRANSPOSED-TILED
//           [b][jb(64)][hd(256)][j(32)].
// ---------------------------------------------------------------------------
__global__ __launch_bounds__(256) void k_gemm(const float* __restrict__ x,
                                              const float* __restrict__ W,
                                              const float* __restrict__ a_src,
                                              const float* __restrict__ a_dst,
                                              unsigned short* __restrict__ hbf,
                                              float* __restrict__ ssrc,
                                              float* __restrict__ sdst) {
    __shared__ __align__(16) float smem[4352];   // xs [0,2176) ws [2176,4352); reused 64x65
    const int tid = threadIdx.x;
    const int m0 = (int)(blockIdx.x >> 2) * 64;
    const int n0 = (int)(blockIdx.x & 3) * 64;
    const int tx = tid & 15, ty = tid >> 4;
    const int b = m0 >> 11;
    const int head = n0 >> 6;

    float4 acc[4];
#pragma unroll
    for (int r = 0; r < 4; ++r) acc[r] = make_float4(0.f, 0.f, 0.f, 0.f);

    for (int k0 = 0; k0 < Dd; k0 += 32) {
        __syncthreads();
#pragma unroll
        for (int s = 0; s < 2; ++s) {
            int slot = tid + s * 256;
            int row = slot >> 3, kv = slot & 7;
            float4 xv = *(const float4*)(x + (size_t)(m0 + row) * Dd + k0 + kv * 4);
            float4 wv = *(const float4*)(W + (size_t)(n0 + row) * Dd + k0 + kv * 4);
            smem[(kv * 4 + 0) * 68 + row] = xv.x; smem[(kv * 4 + 1) * 68 + row] = xv.y;
            smem[(kv * 4 + 2) * 68 + row] = xv.z; smem[(kv * 4 + 3) * 68 + row] = xv.w;
            smem[2176 + (kv * 4 + 0) * 68 + row] = wv.x; smem[2176 + (kv * 4 + 1) * 68 + row] = wv.y;
            smem[2176 + (kv * 4 + 2) * 68 + row] = wv.z; smem[2176 + (kv * 4 + 3) * 68 + row] = wv.w;
        }
        __syncthreads();
#pragma unroll
        for (int kk = 0; kk < 32; ++kk) {
            float4 a = *(const float4*)(smem + kk * 68 + ty * 4);
            float4 bq = *(const float4*)(smem + 2176 + kk * 68 + tx * 4);
            acc[0].x = fmaf(a.x, bq.x, acc[0].x); acc[0].y = fmaf(a.x, bq.y, acc[0].y);
            acc[0].z = fmaf(a.x, bq.z, acc[0].z); acc[0].w = fmaf(a.x, bq.w, acc[0].w);
            acc[1].x = fmaf(a.y, bq.x, acc[1].x); acc[1].y = fmaf(a.y, bq.y, acc[1].y);
            acc[1].z = fmaf(a.y, bq.z, acc[1].z); acc[1].w = fmaf(a.y, bq.w, acc[1].w);
            acc[2].x = fmaf(a.z, bq.x, acc[2].x); acc[2].y = fmaf(a.z, bq.y, acc[2].y);
            acc[2].z = fmaf(a.z, bq.z, acc[2].z); acc[2].w = fmaf(a.z, bq.w, acc[2].w);
            acc[3].x = fmaf(a.w, bq.x, acc[3].x); acc[3].y = fmaf(a.w, bq.y, acc[3].y);
            acc[3].z = fmaf(a.w, bq.z, acc[3].z); acc[3].w = fmaf(a.w, bq.w, acc[3].w);
        }
    }

    // ---- scores epilogue ----
    {
        float4 as4 = *(const float4*)(a_src + head * HDd + tx * 4);
        float4 ad4 = *(const float4*)(a_dst + head * HDd + tx * 4);
#pragma unroll
        for (int r = 0; r < 4; ++r) {
            float ss = acc[r].x * as4.x + acc[r].y * as4.y + acc[r].z * as4.z + acc[r].w * as4.w;
            float sd = acc[r].x * ad4.x + acc[r].y * ad4.y + acc[r].z * ad4.z + acc[r].w * ad4.w;
#pragma unroll
            for (int off = 1; off < 16; off <<= 1) {
                ss += __shfl_xor(ss, off);
                sd += __shfl_xor(sd, off);
            }
            if (tx == 0) {
                int i = (m0 & 2047) + ty * 4 + r;
                ssrc[((size_t)b * Nn + i) * Hh + head] = ss;
                sdst[((size_t)b * Nn + i) * Hh + head] = sd;
            }
        }
    }

    // ---- transpose + bf16 tiled write ----
    __syncthreads();
#pragma unroll
    for (int r = 0; r < 4; ++r) {
        smem[(tx * 4 + 0) * 65 + ty * 4 + r] = acc[r].x;
        smem[(tx * 4 + 1) * 65 + ty * 4 + r] = acc[r].y;
        smem[(tx * 4 + 2) * 65 + ty * 4 + r] = acc[r].z;
        smem[(tx * 4 + 3) * 65 + ty * 4 + r] = acc[r].w;
    }
    __syncthreads();
    if (tid < 128) {
        const int dloc = tid >> 1, jh = tid & 1;
        const float* row = smem + dloc * 65 + jh * 32;
        unsigned pk[16];
#pragma unroll
        for (int jj = 0; jj < 16; ++jj) {
            unsigned u0 = rne_bf16(row[jj * 2]);
            unsigned u1 = rne_bf16(row[jj * 2 + 1]);
            pk[jj] = u0 | (u1 << 16);
        }
        int jbglob = ((m0 & 2047) >> 5) + jh;
        unsigned short* dst = hbf +
            ((size_t)((b * 64 + jbglob) * 256 + head * HDd + dloc)) * 32;
        uint4* d4 = (uint4*)dst;
        d4[0] = make_uint4(pk[0], pk[1], pk[2], pk[3]);
        d4[1] = make_uint4(pk[4], pk[5], pk[6], pk[7]);
        d4[2] = make_uint4(pk[8], pk[9], pk[10], pk[11]);
        d4[3] = make_uint4(pk[12], pk[13], pk[14], pk[15]);
    }
}

// ---------------------------------------------------------------------------
// Kernel 2: MFMA masked-softmax aggregate, EXCLUSIVE ownership (no atomics).
// Block = (b, i-tile 32, head-pair) -> grid 512, full-j sweep (64 steps).
// bid mapping pairs hp=0/1 blocks onto the same XCD (bid, bid+8) so the
// shared adj rows hit L2. Z computed via MFMA with ones-B fragment ->
// register-local normalization. 4 waves: wave = (head_local, d-half).
// ---------------------------------------------------------------------------
__global__ __launch_bounds__(256, 4) void k_aggr(const unsigned short* __restrict__ hbf,
                                                 const float* __restrict__ adj,
                                                 const float* __restrict__ ssrc,
                                                 const float* __restrict__ sdst,
                                                 float* __restrict__ out) {
    __shared__ __align__(16) unsigned short Bh[128 * 40];  // [hl*64+d][j32], 80 B rows
    __shared__ __align__(16) unsigned short Aw[64 * 40];   // [hl*32+i][j32]

    const int tid = threadIdx.x;
    const int bid = (int)blockIdx.x;
    const int hp  = (bid >> 3) & 1;                  // head pair 0 -> h{0,1}, 1 -> h{2,3}
    const int lin = (bid & 7) | ((bid >> 4) << 3);   // 0..255
    const int b  = lin >> 6;
    const int i0 = (lin & 63) * 32;

    // gen mapping: thread = (i, jq): 4 j x 2 heads
    const int gi = tid >> 3;        // 0..31
    const int jq = tid & 7;         // j = jq*4 + jj
    // mfma mapping: wave = (head_local, d-half)
    const int wv = tid >> 6;
    const int hl = wv >> 1, tl = wv & 1;
    const int ln = tid & 63, l15 = ln & 15, l4 = ln >> 4;
    // staging mapping: thread = (row128, half)
    const int srow = tid >> 1, shalf = tid & 1;

    const float2 s2 = *(const float2*)(ssrc + ((size_t)b * Nn + i0 + gi) * Hh + hp * 2);
    const float* adjr = adj + (size_t)b * Nn * Nn + (size_t)(i0 + gi) * Nn;
    const float* sdr = sdst + (size_t)b * Nn * Hh;

    const v8s ones = {0x3F80, 0x3F80, 0x3F80, 0x3F80, 0x3F80, 0x3F80, 0x3F80, 0x3F80};

    v4f acc[2][2], zac[2];
#pragma unroll
    for (int g = 0; g < 2; ++g) {
        zac[g] = (v4f){0.f, 0.f, 0.f, 0.f};
#pragma unroll
        for (int t = 0; t < 2; ++t) acc[g][t] = (v4f){0.f, 0.f, 0.f, 0.f};
    }

    for (int st = 0; st < 64; ++st) {
        const int j0 = st * 32;
        // ---- register prefetch (overlaps previous step's MFMA phase) ----
        const uint4* src = (const uint4*)(hbf +
            ((size_t)((b * 64 + st) * 256 + hp * 128 + srow)) * 32 + shalf * 16);
        uint4 p0 = src[0], p1 = src[1];
        float4 ajv = *(const float4*)(adjr + j0 + jq * 4);
        float4 sdv0 = *(const float4*)(sdr + (size_t)(j0 + jq * 4 + 0) * Hh);
        float4 sdv1 = *(const float4*)(sdr + (size_t)(j0 + jq * 4 + 1) * Hh);
        float4 sdv2 = *(const float4*)(sdr + (size_t)(j0 + jq * 4 + 2) * Hh);
        float4 sdv3 = *(const float4*)(sdr + (size_t)(j0 + jq * 4 + 3) * Hh);
        __syncthreads();   // previous step's LDS readers done
        // ---- stage Bh (conflict-floor b128 writes, stride 40) ----
        {
            uint4* dh = (uint4*)(Bh + srow * 40 + shalf * 16);
            dh[0] = p0; dh[1] = p1;
        }
        // ---- generate w~ (2 heads) into A layout ----
        {
            const float adjv[4] = {ajv.x, ajv.y, ajv.z, ajv.w};
            const float sd0[4] = {sdv0.x, sdv0.y, sdv0.z, sdv0.w};
            const float sd1[4] = {sdv1.x, sdv1.y, sdv1.z, sdv1.w};
            const float sd2[4] = {sdv2.x, sdv2.y, sdv2.z, sdv2.w};
            const float sd3[4] = {sdv3.x, sdv3.y, sdv3.z, sdv3.w};
            unsigned wpk[2][2];
#pragma unroll
            for (int h = 0; h < 2; ++h) {
                const float sh = (h == 0) ? s2.x : s2.y;
                float e0 = sh + sd0[hp * 2 + h];
                float e1 = sh + sd1[hp * 2 + h];
                float e2 = sh + sd2[hp * 2 + h];
                float e3 = sh + sd3[hp * 2 + h];
                e0 = fmaxf(e0, 0.2f * e0); e1 = fmaxf(e1, 0.2f * e1);
                e2 = fmaxf(e2, 0.2f * e2); e3 = fmaxf(e3, 0.2f * e3);
                float w0 = adjv[0] * __expf(e0);
                float w1 = adjv[1] * __expf(e1);
                float w2 = adjv[2] * __expf(e2);
                float w3 = adjv[3] * __expf(e3);
                wpk[h][0] = rne_bf16(w0) | (rne_bf16(w1) << 16);
                wpk[h][1] = rne_bf16(w2) | (rne_bf16(w3) << 16);
            }
#pragma unroll
            for (int h = 0; h < 2; ++h)
                *(uint2*)(Aw + (h * 32 + gi) * 40 + jq * 4) =
                    make_uint2(wpk[h][0], wpk[h][1]);
        }
        __syncthreads();
        // ---- MFMA phase ----
        {
            v8s a0 = *(const v8s*)(Aw + (hl * 32 + l15) * 40 + l4 * 8);
            v8s a1 = *(const v8s*)(Aw + (hl * 32 + 16 + l15) * 40 + l4 * 8);
            v8s b0 = *(const v8s*)(Bh + (hl * 64 + (tl * 2 + 0) * 16 + l15) * 40 + l4 * 8);
            v8s b1 = *(const v8s*)(Bh + (hl * 64 + (tl * 2 + 1) * 16 + l15) * 40 + l4 * 8);
            acc[0][0] = __builtin_amdgcn_mfma_f32_16x16x32_bf16(a0, b0, acc[0][0], 0, 0, 0);
            acc[0][1] = __builtin_amdgcn_mfma_f32_16x16x32_bf16(a0, b1, acc[0][1], 0, 0, 0);
            acc[1][0] = __builtin_amdgcn_mfma_f32_16x16x32_bf16(a1, b0, acc[1][0], 0, 0, 0);
            acc[1][1] = __builtin_amdgcn_mfma_f32_16x16x32_bf16(a1, b1, acc[1][1], 0, 0, 0);
            zac[0] = __builtin_amdgcn_mfma_f32_16x16x32_bf16(a0, ones, zac[0], 0, 0, 0);
            zac[1] = __builtin_amdgcn_mfma_f32_16x16x32_bf16(a1, ones, zac[1], 0, 0, 0);
        }
    }

    // ---- epilogue: register-local normalize + exclusive store ----
    const int head = hp * 2 + hl;
#pragma unroll
    for (int g = 0; g < 2; ++g) {
#pragma unroll
        for (int r = 0; r < 4; ++r) {
            float zinv = 1.f / zac[g][r];
            int i = i0 + g * 16 + l4 * 4 + r;
#pragma unroll
            for (int t = 0; t < 2; ++t) {
                int d = head * HDd + (tl * 2 + t) * 16 + l15;
                out[((size_t)b * Nn + i) * Dd + d] = acc[g][t][r] * zinv;
            }
        }
    }
}

extern "C" void kernel_launch(void* const* d_in, const int* in_sizes, int n_in,
                              void* d_out, int out_size, void* d_ws, size_t ws_size,
                              hipStream_t stream) {
    const float* x     = (const float*)d_in[0];
    const float* adj   = (const float*)d_in[1];
    const float* W     = (const float*)d_in[2];
    const float* a_src = (const float*)d_in[3];
    const float* a_dst = (const float*)d_in[4];
    float* out = (float*)d_out;

    // ws: hbf 4MB | ssrc 128KB | sdst 128KB
    unsigned short* hbf = (unsigned short*)d_ws;
    float* ssrc = (float*)(hbf + (size_t)Bb * Nn * Dd);
    float* sdst = ssrc + (size_t)Bb * Nn * Hh;

    k_gemm<<<dim3(512), dim3(256), 0, stream>>>(x, W, a_src, a_dst, hbf, ssrc, sdst);
    k_aggr<<<dim3(512), dim3(256), 0, stream>>>(hbf, adj, ssrc, sdst, out);
}

// Round 6
// 156.133 us; speedup vs baseline: 1.3305x; 1.1959x over previous
//
#include <hip/hip_runtime.h>
#include <math.h>

#define Bb   4
#define Nn   2048
#define Dd   256
#define Hh   4
#define HDd  64

typedef float v4f __attribute__((ext_vector_type(4)));
typedef short v8s __attribute__((ext_vector_type(8)));

__device__ __forceinline__ unsigned rne_bf16(float f) {
    unsigned u = __float_as_uint(f);
    u += 0x7fffu + ((u >> 16) & 1u);
    return u >> 16;
}

// ---------------------------------------------------------------------------
// Kernel 1: h = x @ W.T via MFMA, hi/lo bf16 split (err ~2^-17).
// Block = 256 thr (4 waves), C-tile 64m x 64n (n-tile == one head), grid 512.
// K loop: 4 steps of 64; staging casts fp32 -> bf16 hi/lo in-register.
// acc += xh*wh + xl*wh + xh*wl  (3 MFMAs per tile per k-half).
// Epilogue: fp32 C -> LDS [d][m] (stride 67); scores s_src/s_dst from T;
//           h -> bf16 TRANSPOSED-TILED hbf [b][jb(64)][hd(256)][j(32)].
// ---------------------------------------------------------------------------
__global__ __launch_bounds__(256, 2) void k_gemm(const float* __restrict__ x,
                                                 const float* __restrict__ W,
                                                 const float* __restrict__ a_src,
                                                 const float* __restrict__ a_dst,
                                                 unsigned short* __restrict__ hbf,
                                                 float* __restrict__ ssrc,
                                                 float* __restrict__ sdst) {
    __shared__ __align__(16) unsigned short xs[2][64 * 72];  // hi, lo  (T reuses xs)
    __shared__ __align__(16) unsigned short wsm[2][64 * 72];
    __shared__ float asd[128];

    const int tid = threadIdx.x;
    const int m0 = (int)(blockIdx.x >> 2) * 64;
    const int head = (int)blockIdx.x & 3;
    const int n0 = head * 64;
    const int b = m0 >> 11;
    const int i0loc = m0 & 2047;

    if (tid < 128) {
        int sel = tid >> 6, d = tid & 63;
        asd[tid] = sel ? a_dst[n0 + d] : a_src[n0 + d];
    }

    const int wv = tid >> 6, ln = tid & 63, l15 = ln & 15, l4 = ln >> 4;
    const int mh = wv >> 1, nh = wv & 1;
    const int srow = tid >> 2, kq = (tid & 3) * 16;   // staging: row, k-offset (shorts)

    v4f acc[2][2];
#pragma unroll
    for (int g = 0; g < 2; ++g)
#pragma unroll
        for (int t = 0; t < 2; ++t) acc[g][t] = (v4f){0.f, 0.f, 0.f, 0.f};

    for (int st = 0; st < 4; ++st) {
        const int k0 = st * 64;
        __syncthreads();
        // ---- stage x and W tiles as bf16 hi/lo ----
        {
            float xf[16], wf[16];
            const float* xp = x + (size_t)(m0 + srow) * Dd + k0 + kq;
            const float* wp = W + (size_t)(n0 + srow) * Dd + k0 + kq;
#pragma unroll
            for (int q = 0; q < 4; ++q) {
                *(float4*)&xf[q * 4] = *(const float4*)(xp + q * 4);
                *(float4*)&wf[q * 4] = *(const float4*)(wp + q * 4);
            }
            unsigned xh[8], xl[8], wh[8], wl[8];
#pragma unroll
            for (int j = 0; j < 8; ++j) {
                unsigned h0 = rne_bf16(xf[2 * j]), h1 = rne_bf16(xf[2 * j + 1]);
                float l0 = xf[2 * j] - __uint_as_float(h0 << 16);
                float l1 = xf[2 * j + 1] - __uint_as_float(h1 << 16);
                xh[j] = h0 | (h1 << 16);
                xl[j] = rne_bf16(l0) | (rne_bf16(l1) << 16);
                unsigned g0 = rne_bf16(wf[2 * j]), g1 = rne_bf16(wf[2 * j + 1]);
                float m0f = wf[2 * j] - __uint_as_float(g0 << 16);
                float m1f = wf[2 * j + 1] - __uint_as_float(g1 << 16);
                wh[j] = g0 | (g1 << 16);
                wl[j] = rne_bf16(m0f) | (rne_bf16(m1f) << 16);
            }
            *(uint4*)(xs[0] + srow * 72 + kq)     = make_uint4(xh[0], xh[1], xh[2], xh[3]);
            *(uint4*)(xs[0] + srow * 72 + kq + 8) = make_uint4(xh[4], xh[5], xh[6], xh[7]);
            *(uint4*)(xs[1] + srow * 72 + kq)     = make_uint4(xl[0], xl[1], xl[2], xl[3]);
            *(uint4*)(xs[1] + srow * 72 + kq + 8) = make_uint4(xl[4], xl[5], xl[6], xl[7]);
            *(uint4*)(wsm[0] + srow * 72 + kq)     = make_uint4(wh[0], wh[1], wh[2], wh[3]);
            *(uint4*)(wsm[0] + srow * 72 + kq + 8) = make_uint4(wh[4], wh[5], wh[6], wh[7]);
            *(uint4*)(wsm[1] + srow * 72 + kq)     = make_uint4(wl[0], wl[1], wl[2], wl[3]);
            *(uint4*)(wsm[1] + srow * 72 + kq + 8) = make_uint4(wl[4], wl[5], wl[6], wl[7]);
        }
        __syncthreads();
        // ---- MFMA: wave (mh, nh) owns 2x2 16-tiles ----
        {
            v8s ah[2][2], al[2][2], bh_[2][2], bl_[2][2];
#pragma unroll
            for (int g = 0; g < 2; ++g)
#pragma unroll
                for (int kh = 0; kh < 2; ++kh) {
                    int ro = (mh * 32 + g * 16 + l15) * 72 + kh * 32 + l4 * 8;
                    ah[g][kh] = *(const v8s*)(xs[0] + ro);
                    al[g][kh] = *(const v8s*)(xs[1] + ro);
                }
#pragma unroll
            for (int t = 0; t < 2; ++t)
#pragma unroll
                for (int kh = 0; kh < 2; ++kh) {
                    int ro = (nh * 32 + t * 16 + l15) * 72 + kh * 32 + l4 * 8;
                    bh_[t][kh] = *(const v8s*)(wsm[0] + ro);
                    bl_[t][kh] = *(const v8s*)(wsm[1] + ro);
                }
#pragma unroll
            for (int g = 0; g < 2; ++g)
#pragma unroll
                for (int t = 0; t < 2; ++t)
#pragma unroll
                    for (int kh = 0; kh < 2; ++kh) {
                        acc[g][t] = __builtin_amdgcn_mfma_f32_16x16x32_bf16(ah[g][kh], bh_[t][kh], acc[g][t], 0, 0, 0);
                        acc[g][t] = __builtin_amdgcn_mfma_f32_16x16x32_bf16(al[g][kh], bh_[t][kh], acc[g][t], 0, 0, 0);
                        acc[g][t] = __builtin_amdgcn_mfma_f32_16x16x32_bf16(ah[g][kh], bl_[t][kh], acc[g][t], 0, 0, 0);
                    }
        }
    }

    // ---- epilogue: C -> T[d][m] (stride 67) ----
    __syncthreads();
    float* T = (float*)&xs[0][0];   // 64*67*4 = 17168 B <= 18432
#pragma unroll
    for (int g = 0; g < 2; ++g)
#pragma unroll
        for (int t = 0; t < 2; ++t)
#pragma unroll
            for (int r = 0; r < 4; ++r) {
                int d = nh * 32 + t * 16 + l15;
                int m = mh * 32 + g * 16 + l4 * 4 + r;
                T[d * 67 + m] = acc[g][t][r];
            }
    __syncthreads();
    if (tid < 128) {
        // scores
        int m = tid & 63, sel = tid >> 6;
        float s = 0.f;
#pragma unroll
        for (int d = 0; d < 64; ++d) s += T[d * 67 + m] * asd[sel * 64 + d];
        (sel ? sdst : ssrc)[((size_t)b * Nn + i0loc + m) * Hh + head] = s;
        // hbf pack
        int dloc = tid >> 1, jh = tid & 1;
        const float* row = T + dloc * 67 + jh * 32;
        unsigned pk[16];
#pragma unroll
        for (int jj = 0; jj < 16; ++jj)
            pk[jj] = rne_bf16(row[jj * 2]) | (rne_bf16(row[jj * 2 + 1]) << 16);
        unsigned short* dst = hbf +
            ((size_t)((b * 64 + (i0loc >> 5) + jh) * 256 + head * HDd + dloc)) * 32;
        uint4* d4 = (uint4*)dst;
        d4[0] = make_uint4(pk[0], pk[1], pk[2], pk[3]);
        d4[1] = make_uint4(pk[4], pk[5], pk[6], pk[7]);
        d4[2] = make_uint4(pk[8], pk[9], pk[10], pk[11]);
        d4[3] = make_uint4(pk[12], pk[13], pk[14], pk[15]);
    }
}

// ---------------------------------------------------------------------------
// Kernel 2: MFMA masked-softmax aggregate, exclusive ownership, no atomics.
// Block = 512 thr (8 waves) <-> (b, i-tile 32, head-pair); grid 512
// (2 blocks/CU = 16 waves/CU). j-tile 64/step, 32 steps (half the barriers).
// All LDS rows stride 72 shorts -> every b128/b64 at the 8-access/bank floor.
// Z via ones-MFMA (register-aligned with acc rows). Waves: (hl, d-quarter).
// ---------------------------------------------------------------------------
__global__ __launch_bounds__(512, 4) void k_aggr(const unsigned short* __restrict__ hbf,
                                                 const float* __restrict__ adj,
                                                 const float* __restrict__ ssrc,
                                                 const float* __restrict__ sdst,
                                                 float* __restrict__ out) {
    __shared__ __align__(16) unsigned short Bh[128 * 72];  // [hl*64+d][j64]  18.4 KB
    __shared__ __align__(16) unsigned short Aw[64 * 72];   // [hl*32+i][j64]   9.2 KB

    const int tid = threadIdx.x;
    const int bid = (int)blockIdx.x;
    const int hp  = (bid >> 3) & 1;                  // head pair
    const int lin = (bid & 7) | ((bid >> 4) << 3);   // XCD-paired (b, i-tile)
    const int b  = lin >> 6;
    const int i0 = (lin & 63) * 32;

    // gen: thread = (gi 0..31, jq 0..15) -> 4 j x 2 heads
    const int gi = tid >> 4, jq = tid & 15;
    // staging: thread = (srow 0..127, sseg 0..3) -> 16 shorts
    const int srow = tid >> 2, sseg = tid & 3;
    // mfma: wave = (hl, tl d-quarter)
    const int wv = tid >> 6;
    const int hl = wv >> 2, tl = wv & 3;
    const int ln = tid & 63, l15 = ln & 15, l4 = ln >> 4;

    const float2 s2 = *(const float2*)(ssrc + ((size_t)b * Nn + i0 + gi) * Hh + hp * 2);
    const float* adjr = adj + (size_t)b * Nn * Nn + (size_t)(i0 + gi) * Nn;
    const float* sdr = sdst + (size_t)b * Nn * Hh + hp * 2;

    const v8s ones = {0x3F80, 0x3F80, 0x3F80, 0x3F80, 0x3F80, 0x3F80, 0x3F80, 0x3F80};

    v4f acc[2], zac[2];
#pragma unroll
    for (int g = 0; g < 2; ++g) {
        acc[g] = (v4f){0.f, 0.f, 0.f, 0.f};
        zac[g] = (v4f){0.f, 0.f, 0.f, 0.f};
    }

    for (int st = 0; st < 32; ++st) {
        const int j0 = st * 64;
        // ---- register prefetch ----
        const uint4* src = (const uint4*)(hbf +
            ((size_t)((b * 64 + 2 * st + (sseg >> 1)) * 256 + hp * 128 + srow)) * 32 +
            (sseg & 1) * 16);
        uint4 p0 = src[0], p1 = src[1];
        float4 ajv = *(const float4*)(adjr + j0 + jq * 4);
        float2 sd0 = *(const float2*)(sdr + (size_t)(j0 + jq * 4 + 0) * Hh);
        float2 sd1 = *(const float2*)(sdr + (size_t)(j0 + jq * 4 + 1) * Hh);
        float2 sd2 = *(const float2*)(sdr + (size_t)(j0 + jq * 4 + 2) * Hh);
        float2 sd3 = *(const float2*)(sdr + (size_t)(j0 + jq * 4 + 3) * Hh);
        __syncthreads();   // previous step's LDS readers done
        // ---- stage Bh ----
        {
            uint4* dh = (uint4*)(Bh + srow * 72 + sseg * 16);
            dh[0] = p0; dh[1] = p1;
        }
        // ---- gen w~ (2 heads) into Aw ----
        {
            const float adjv[4] = {ajv.x, ajv.y, ajv.z, ajv.w};
            const float2 sdv[4] = {sd0, sd1, sd2, sd3};
            unsigned pk0[2], pk1[2];
#pragma unroll
            for (int k = 0; k < 4; ++k) {
                float e0 = s2.x + sdv[k].x;
                float e1 = s2.y + sdv[k].y;
                e0 = fmaxf(e0, 0.2f * e0);
                e1 = fmaxf(e1, 0.2f * e1);
                unsigned u0 = rne_bf16(adjv[k] * __expf(e0));
                unsigned u1 = rne_bf16(adjv[k] * __expf(e1));
                if (k & 1) { pk0[k >> 1] |= u0 << 16; pk1[k >> 1] |= u1 << 16; }
                else       { pk0[k >> 1] = u0;        pk1[k >> 1] = u1; }
            }
            *(uint2*)(Aw + (gi) * 72 + jq * 4)      = make_uint2(pk0[0], pk0[1]);
            *(uint2*)(Aw + (32 + gi) * 72 + jq * 4) = make_uint2(pk1[0], pk1[1]);
        }
        __syncthreads();
        // ---- MFMA: wave (hl, tl) ----
        {
            v8s a[2][2], bf[2];
#pragma unroll
            for (int g = 0; g < 2; ++g)
#pragma unroll
                for (int kh = 0; kh < 2; ++kh)
                    a[g][kh] = *(const v8s*)(Aw + (hl * 32 + g * 16 + l15) * 72 + kh * 32 + l4 * 8);
#pragma unroll
            for (int kh = 0; kh < 2; ++kh)
                bf[kh] = *(const v8s*)(Bh + (hl * 64 + tl * 16 + l15) * 72 + kh * 32 + l4 * 8);
#pragma unroll
            for (int g = 0; g < 2; ++g)
#pragma unroll
                for (int kh = 0; kh < 2; ++kh) {
                    acc[g] = __builtin_amdgcn_mfma_f32_16x16x32_bf16(a[g][kh], bf[kh], acc[g], 0, 0, 0);
                    zac[g] = __builtin_amdgcn_mfma_f32_16x16x32_bf16(a[g][kh], ones, zac[g], 0, 0, 0);
                }
        }
    }

    // ---- epilogue: register-local normalize + exclusive store ----
    const int head = hp * 2 + hl;
    const int d = head * HDd + tl * 16 + l15;
#pragma unroll
    for (int g = 0; g < 2; ++g)
#pragma unroll
        for (int r = 0; r < 4; ++r) {
            float zinv = 1.f / zac[g][r];
            int i = i0 + g * 16 + l4 * 4 + r;
            out[((size_t)b * Nn + i) * Dd + d] = acc[g][r] * zinv;
        }
}

extern "C" void kernel_launch(void* const* d_in, const int* in_sizes, int n_in,
                              void* d_out, int out_size, void* d_ws, size_t ws_size,
                              hipStream_t stream) {
    const float* x     = (const float*)d_in[0];
    const float* adj   = (const float*)d_in[1];
    const float* W     = (const float*)d_in[2];
    const float* a_src = (const float*)d_in[3];
    const float* a_dst = (const float*)d_in[4];
    float* out = (float*)d_out;

    // ws: hbf 4MB | ssrc 128KB | sdst 128KB
    unsigned short* hbf = (unsigned short*)d_ws;
    float* ssrc = (float*)(hbf + (size_t)Bb * Nn * Dd);
    float* sdst = ssrc + (size_t)Bb * Nn * Hh;

    k_gemm<<<dim3(512), dim3(256), 0, stream>>>(x, W, a_src, a_dst, hbf, ssrc, sdst);
    k_aggr<<<dim3(512), dim3(512), 0, stream>>>(hbf, adj, ssrc, sdst, out);
}

// Round 8
// 155.407 us; speedup vs baseline: 1.3367x; 1.0047x over previous
//
#include <hip/hip_runtime.h>
#include <math.h>

#define Bb   4
#define Nn   2048
#define Dd   256
#define Hh   4
#define HDd  64
#define BN   (Bb * Nn)

typedef float v4f __attribute__((ext_vector_type(4)));
typedef short v8s __attribute__((ext_vector_type(8)));

__device__ __forceinline__ unsigned rne_bf16(float f) {
    unsigned u = __float_as_uint(f);
    u += 0x7fffu + ((u >> 16) & 1u);
    return u >> 16;
}

// ---------------------------------------------------------------------------
// Kernel 1: h = x @ W.T via MFMA, hi/lo bf16 split (err ~2^-17).
// Block = 256 thr (4 waves), C-tile 64m x 64n (n-tile == one head), grid 512.
// Epilogue: scores s_src/s_dst written TRANSPOSED [h][bn]; h -> bf16
// TRANSPOSED-TILED hbf [b][jb(64)][hd(256)][j(32)]  (== MFMA B-frag layout).
// ---------------------------------------------------------------------------
__global__ __launch_bounds__(256, 2) void k_gemm(const float* __restrict__ x,
                                                 const float* __restrict__ W,
                                                 const float* __restrict__ a_src,
                                                 const float* __restrict__ a_dst,
                                                 unsigned short* __restrict__ hbf,
                                                 float* __restrict__ ssrc,
                                                 float* __restrict__ sdst) {
    __shared__ __align__(16) unsigned short xs[2][64 * 72];  // hi, lo  (T reuses xs)
    __shared__ __align__(16) unsigned short wsm[2][64 * 72];
    __shared__ float asd[128];

    const int tid = threadIdx.x;
    const int m0 = (int)(blockIdx.x >> 2) * 64;
    const int head = (int)blockIdx.x & 3;
    const int n0 = head * 64;
    const int b = m0 >> 11;
    const int i0loc = m0 & 2047;

    if (tid < 128) {
        int sel = tid >> 6, d = tid & 63;
        asd[tid] = sel ? a_dst[n0 + d] : a_src[n0 + d];
    }

    const int wv = tid >> 6, ln = tid & 63, l15 = ln & 15, l4 = ln >> 4;
    const int mh = wv >> 1, nh = wv & 1;
    const int srow = tid >> 2, kq = (tid & 3) * 16;

    v4f acc[2][2];
#pragma unroll
    for (int g = 0; g < 2; ++g)
#pragma unroll
        for (int t = 0; t < 2; ++t) acc[g][t] = (v4f){0.f, 0.f, 0.f, 0.f};

    for (int st = 0; st < 4; ++st) {
        const int k0 = st * 64;
        __syncthreads();
        // ---- stage x and W tiles as bf16 hi/lo ----
        {
            float xf[16], wf[16];
            const float* xp = x + (size_t)(m0 + srow) * Dd + k0 + kq;
            const float* wp = W + (size_t)(n0 + srow) * Dd + k0 + kq;
#pragma unroll
            for (int q = 0; q < 4; ++q) {
                *(float4*)&xf[q * 4] = *(const float4*)(xp + q * 4);
                *(float4*)&wf[q * 4] = *(const float4*)(wp + q * 4);
            }
            unsigned xh[8], xl[8], wh[8], wl[8];
#pragma unroll
            for (int j = 0; j < 8; ++j) {
                unsigned h0 = rne_bf16(xf[2 * j]), h1 = rne_bf16(xf[2 * j + 1]);
                float l0 = xf[2 * j] - __uint_as_float(h0 << 16);
                float l1 = xf[2 * j + 1] - __uint_as_float(h1 << 16);
                xh[j] = h0 | (h1 << 16);
                xl[j] = rne_bf16(l0) | (rne_bf16(l1) << 16);
                unsigned g0 = rne_bf16(wf[2 * j]), g1 = rne_bf16(wf[2 * j + 1]);
                float m0f = wf[2 * j] - __uint_as_float(g0 << 16);
                float m1f = wf[2 * j + 1] - __uint_as_float(g1 << 16);
                wh[j] = g0 | (g1 << 16);
                wl[j] = rne_bf16(m0f) | (rne_bf16(m1f) << 16);
            }
            *(uint4*)(xs[0] + srow * 72 + kq)     = make_uint4(xh[0], xh[1], xh[2], xh[3]);
            *(uint4*)(xs[0] + srow * 72 + kq + 8) = make_uint4(xh[4], xh[5], xh[6], xh[7]);
            *(uint4*)(xs[1] + srow * 72 + kq)     = make_uint4(xl[0], xl[1], xl[2], xl[3]);
            *(uint4*)(xs[1] + srow * 72 + kq + 8) = make_uint4(xl[4], xl[5], xl[6], xl[7]);
            *(uint4*)(wsm[0] + srow * 72 + kq)     = make_uint4(wh[0], wh[1], wh[2], wh[3]);
            *(uint4*)(wsm[0] + srow * 72 + kq + 8) = make_uint4(wh[4], wh[5], wh[6], wh[7]);
            *(uint4*)(wsm[1] + srow * 72 + kq)     = make_uint4(wl[0], wl[1], wl[2], wl[3]);
            *(uint4*)(wsm[1] + srow * 72 + kq + 8) = make_uint4(wl[4], wl[5], wl[6], wl[7]);
        }
        __syncthreads();
        // ---- MFMA: wave (mh, nh) owns 2x2 16-tiles ----
        {
            v8s ah[2][2], al[2][2], bh_[2][2], bl_[2][2];
#pragma unroll
            for (int g = 0; g < 2; ++g)
#pragma unroll
                for (int kh = 0; kh < 2; ++kh) {
                    int ro = (mh * 32 + g * 16 + l15) * 72 + kh * 32 + l4 * 8;
                    ah[g][kh] = *(const v8s*)(xs[0] + ro);
                    al[g][kh] = *(const v8s*)(xs[1] + ro);
                }
#pragma unroll
            for (int t = 0; t < 2; ++t)
#pragma unroll
                for (int kh = 0; kh < 2; ++kh) {
                    int ro = (nh * 32 + t * 16 + l15) * 72 + kh * 32 + l4 * 8;
                    bh_[t][kh] = *(const v8s*)(wsm[0] + ro);
                    bl_[t][kh] = *(const v8s*)(wsm[1] + ro);
                }
#pragma unroll
            for (int g = 0; g < 2; ++g)
#pragma unroll
                for (int t = 0; t < 2; ++t)
#pragma unroll
                    for (int kh = 0; kh < 2; ++kh) {
                        acc[g][t] = __builtin_amdgcn_mfma_f32_16x16x32_bf16(ah[g][kh], bh_[t][kh], acc[g][t], 0, 0, 0);
                        acc[g][t] = __builtin_amdgcn_mfma_f32_16x16x32_bf16(al[g][kh], bh_[t][kh], acc[g][t], 0, 0, 0);
                        acc[g][t] = __builtin_amdgcn_mfma_f32_16x16x32_bf16(ah[g][kh], bl_[t][kh], acc[g][t], 0, 0, 0);
                    }
        }
    }

    // ---- epilogue: C -> T[d][m] (stride 67) ----
    __syncthreads();
    float* T = (float*)&xs[0][0];   // 64*67*4 = 17168 B
#pragma unroll
    for (int g = 0; g < 2; ++g)
#pragma unroll
        for (int t = 0; t < 2; ++t)
#pragma unroll
            for (int r = 0; r < 4; ++r) {
                int d = nh * 32 + t * 16 + l15;
                int m = mh * 32 + g * 16 + l4 * 4 + r;
                T[d * 67 + m] = acc[g][t][r];
            }
    __syncthreads();
    if (tid < 128) {
        // scores -> TRANSPOSED [h][bn]
        int m = tid & 63, sel = tid >> 6;
        float s = 0.f;
#pragma unroll
        for (int d = 0; d < 64; ++d) s += T[d * 67 + m] * asd[sel * 64 + d];
        (sel ? sdst : ssrc)[(size_t)head * BN + (size_t)b * Nn + i0loc + m] = s;
        // hbf pack
        int dloc = tid >> 1, jh = tid & 1;
        const float* row = T + dloc * 67 + jh * 32;
        unsigned pk[16];
#pragma unroll
        for (int jj = 0; jj < 16; ++jj)
            pk[jj] = rne_bf16(row[jj * 2]) | (rne_bf16(row[jj * 2 + 1]) << 16);
        unsigned short* dst = hbf +
            ((size_t)((b * 64 + (i0loc >> 5) + jh) * 256 + head * HDd + dloc)) * 32;
        uint4* d4 = (uint4*)dst;
        d4[0] = make_uint4(pk[0], pk[1], pk[2], pk[3]);
        d4[1] = make_uint4(pk[4], pk[5], pk[6], pk[7]);
        d4[2] = make_uint4(pk[8], pk[9], pk[10], pk[11]);
        d4[3] = make_uint4(pk[12], pk[13], pk[14], pk[15]);
    }
}

// ---------------------------------------------------------------------------
// Kernel 2: MFMA masked-softmax aggregate, exclusive ownership, no atomics.
// B-fragments loaded DIRECTLY from hbf (already in B-frag layout) — no Bh
// staging, no vmem drain at barriers. Only the w~ A-tile goes through LDS,
// double-buffered -> ONE barrier per step. adj/sdst prefetched after the
// barrier (one MFMA phase of latency cover). Z via ones-MFMA.
// Block = 512 thr = 8 waves (hl, tl d-quarter) <-> (b, i-tile 32, head-pair).
// ---------------------------------------------------------------------------
__global__ __launch_bounds__(512, 4) void k_aggr(const unsigned short* __restrict__ hbf,
                                                 const float* __restrict__ adj,
                                                 const float* __restrict__ ssrc,
                                                 const float* __restrict__ sdst,
                                                 float* __restrict__ out) {
    __shared__ __align__(16) unsigned short Aw[2][64 * 72];   // dbuf, 18.4 KB

    const int tid = threadIdx.x;
    const int bid = (int)blockIdx.x;
    const int hp  = (bid >> 3) & 1;                  // head pair
    const int lin = (bid & 7) | ((bid >> 4) << 3);   // XCD-paired (b, i-tile)
    const int b  = lin >> 6;
    const int i0 = (lin & 63) * 32;

    // gen: thread = (gi 0..31, jq 0..15) -> 4 j x 2 heads
    const int gi = tid >> 4, jq = tid & 15;
    // mfma: wave = (hl, tl d-quarter)
    const int wv = tid >> 6;
    const int hl = wv >> 2, tl = wv & 3;
    const int ln = tid & 63, l15 = ln & 15, l4 = ln >> 4;

    const float ss0 = ssrc[(size_t)(hp * 2 + 0) * BN + (size_t)b * Nn + i0 + gi];
    const float ss1 = ssrc[(size_t)(hp * 2 + 1) * BN + (size_t)b * Nn + i0 + gi];
    const float* adjr = adj + (size_t)b * Nn * Nn + (size_t)(i0 + gi) * Nn;
    const float* sdr0 = sdst + (size_t)(hp * 2 + 0) * BN + (size_t)b * Nn;
    const float* sdr1 = sdst + (size_t)(hp * 2 + 1) * BN + (size_t)b * Nn;

    // B-frag row pointer (hbf is already in B-fragment layout)
    const unsigned short* hrow = hbf +
        ((size_t)b * 64 * 256 + (size_t)(hp * 128 + hl * 64 + tl * 16 + l15)) * 32 + l4 * 8;

    const v8s ones = {0x3F80, 0x3F80, 0x3F80, 0x3F80, 0x3F80, 0x3F80, 0x3F80, 0x3F80};

    v4f acc[2], zac[2];
#pragma unroll
    for (int g = 0; g < 2; ++g) {
        acc[g] = (v4f){0.f, 0.f, 0.f, 0.f};
        zac[g] = (v4f){0.f, 0.f, 0.f, 0.f};
    }

    // prefetch step 0
    float4 ajv = *(const float4*)(adjr + jq * 4);
    float4 sda = *(const float4*)(sdr0 + jq * 4);
    float4 sdb = *(const float4*)(sdr1 + jq * 4);

    for (int st = 0; st < 32; ++st) {
        // ---- gen w~ (2 heads) from pf regs into Aw[st&1] ----
        {
            const float adjv[4] = {ajv.x, ajv.y, ajv.z, ajv.w};
            const float sa[4] = {sda.x, sda.y, sda.z, sda.w};
            const float sb[4] = {sdb.x, sdb.y, sdb.z, sdb.w};
            unsigned pk0[2], pk1[2];
#pragma unroll
            for (int k = 0; k < 4; ++k) {
                float e0 = ss0 + sa[k];
                float e1 = ss1 + sb[k];
                e0 = fmaxf(e0, 0.2f * e0);
                e1 = fmaxf(e1, 0.2f * e1);
                unsigned u0 = rne_bf16(adjv[k] * __expf(e0));
                unsigned u1 = rne_bf16(adjv[k] * __expf(e1));
                if (k & 1) { pk0[k >> 1] |= u0 << 16; pk1[k >> 1] |= u1 << 16; }
                else       { pk0[k >> 1] = u0;        pk1[k >> 1] = u1; }
            }
            *(uint2*)(Aw[st & 1] + gi * 72 + jq * 4)        = make_uint2(pk0[0], pk0[1]);
            *(uint2*)(Aw[st & 1] + (32 + gi) * 72 + jq * 4) = make_uint2(pk1[0], pk1[1]);
        }
        __syncthreads();   // vmem naturally drained (pf consumed above)
        // ---- prefetch next step (covered by MFMA phase below) ----
        {
            const int jn = ((st + 1) & 31) * 64;
            ajv = *(const float4*)(adjr + jn + jq * 4);
            sda = *(const float4*)(sdr0 + jn + jq * 4);
            sdb = *(const float4*)(sdr1 + jn + jq * 4);
        }
        // ---- MFMA phase: B direct from global (L2), A from Aw[st&1] ----
        {
            const unsigned short* awp = Aw[st & 1];
            v8s b0 = *(const v8s*)(hrow + (size_t)(2 * st + 0) * 8192);
            v8s b1 = *(const v8s*)(hrow + (size_t)(2 * st + 1) * 8192);
            v8s a00 = *(const v8s*)(awp + (hl * 32 + l15) * 72 + l4 * 8);
            v8s a01 = *(const v8s*)(awp + (hl * 32 + l15) * 72 + 32 + l4 * 8);
            v8s a10 = *(const v8s*)(awp + (hl * 32 + 16 + l15) * 72 + l4 * 8);
            v8s a11 = *(const v8s*)(awp + (hl * 32 + 16 + l15) * 72 + 32 + l4 * 8);
            acc[0] = __builtin_amdgcn_mfma_f32_16x16x32_bf16(a00, b0, acc[0], 0, 0, 0);
            acc[0] = __builtin_amdgcn_mfma_f32_16x16x32_bf16(a01, b1, acc[0], 0, 0, 0);
            acc[1] = __builtin_amdgcn_mfma_f32_16x16x32_bf16(a10, b0, acc[1], 0, 0, 0);
            acc[1] = __builtin_amdgcn_mfma_f32_16x16x32_bf16(a11, b1, acc[1], 0, 0, 0);
            zac[0] = __builtin_amdgcn_mfma_f32_16x16x32_bf16(a00, ones, zac[0], 0, 0, 0);
            zac[0] = __builtin_amdgcn_mfma_f32_16x16x32_bf16(a01, ones, zac[0], 0, 0, 0);
            zac[1] = __builtin_amdgcn_mfma_f32_16x16x32_bf16(a10, ones, zac[1], 0, 0, 0);
            zac[1] = __builtin_amdgcn_mfma_f32_16x16x32_bf16(a11, ones, zac[1], 0, 0, 0);
        }
    }

    // ---- epilogue: register-local normalize + exclusive store ----
    const int head = hp * 2 + hl;
    const int d = head * HDd + tl * 16 + l15;
#pragma unroll
    for (int g = 0; g < 2; ++g)
#pragma unroll
        for (int r = 0; r < 4; ++r) {
            float zinv = 1.f / zac[g][r];
            int i = i0 + g * 16 + l4 * 4 + r;
            out[((size_t)b * Nn + i) * Dd + d] = acc[g][r] * zinv;
        }
}

extern "C" void kernel_launch(void* const* d_in, const int* in_sizes, int n_in,
                              void* d_out, int out_size, void* d_ws, size_t ws_size,
                              hipStream_t stream) {
    const float* x     = (const float*)d_in[0];
    const float* adj   = (const float*)d_in[1];
    const float* W     = (const float*)d_in[2];
    const float* a_src = (const float*)d_in[3];
    const float* a_dst = (const float*)d_in[4];
    float* out = (float*)d_out;

    // ws: hbf 4MB | ssrc [h][bn] 128KB | sdst [h][bn] 128KB
    // (R7 BUG was here: sdst = ssrc + BN overlapped ssrc's h=1..3 planes)
    unsigned short* hbf = (unsigned short*)d_ws;
    float* ssrc = (float*)(hbf + (size_t)Bb * Nn * Dd);
    float* sdst = ssrc + (size_t)Hh * BN;

    k_gemm<<<dim3(512), dim3(256), 0, stream>>>(x, W, a_src, a_dst, hbf, ssrc, sdst);
    k_aggr<<<dim3(512), dim3(512), 0, stream>>>(hbf, adj, ssrc, sdst, out);
}